// Round 4
// baseline (35.046 us; speedup 1.0000x reference)
//
#include <hip/hip_runtime.h>
#include <math.h>

// Dims fixed by reference setup_inputs():
//   x   : (NS=1024, NN=192) f32 in {-1,+1}
//   W2  : (DD=24)           f32
//   W3  : (DD, DD)          f32
//   phi : (NN, 2)           f32
//   nd  : (NN, NN)          i32 in [0, DD), SYMMETRIC
// out  : (NS,) f32 = J2 + J3 + logmf
//
// c[j,r] = sum_i x_i [nd[j,i]==r] = 2*popc(M[j][r] & P[n]) - popc(M[j][r])
// out[n] = sum_j [ x_j*(0.5*<c_j,W2> + c_j^T W3 c_j) + log(phi[j, x_j>0]) ]
//
// Single fused kernel: grid (NS/64, NN/8), block 512 (8 waves).
// Block (bx,by): samples n0..n0+63, wave wv owns j = by*8+wv.
//   Phase A: pack P sign bits for the 64 samples (ballots)      -> LDS Pp
//   Phase B: build M masks for the 8 j's (ballots over nd rows) -> LDS Msk
//   Phase C: per wave: c[] via popcounts, quadratic form with W3 read
//            through the scalar pipe (uniform addr -> s_load, free operands),
//            phi-log folded in, LDS block reduce, 1 atomic per (block, n).

#define NS 1024
#define NN 192
#define DD 24

typedef unsigned long long ull;

__global__ __launch_bounds__(512) void fused_kernel(
    const float* __restrict__ x,
    const float* __restrict__ W2,
    const float* __restrict__ W3,
    const float* __restrict__ phi,
    const int*   __restrict__ nd,
    float* __restrict__ out)
{
    const int tid  = threadIdx.x;
    const int lane = tid & 63;
    const int wv   = tid >> 6;          // 0..7
    const int n0   = blockIdx.x * 64;
    const int j    = blockIdx.y * 8 + wv;   // wave-uniform

    __shared__ unsigned Pp[64][6];      // sign bits per sample
    __shared__ unsigned Msk[8][24][8];  // per-j,r: 6 mask words, [6]=-(float)cnt, [7] pad
    __shared__ float    part[8][64];

    // ---- Phase A: wave wv packs samples wv*8 .. wv*8+7 ----
    #pragma unroll
    for (int q = 0; q < 8; ++q) {
        const int s = wv * 8 + q;
        const float* xr = &x[(size_t)(n0 + s) * NN];
        unsigned keep = 0;
        #pragma unroll
        for (int c = 0; c < 3; ++c) {
            const float v = xr[c * 64 + lane];
            const ull m = __ballot(v > 0.0f);
            const unsigned lo = (unsigned)m, hi = (unsigned)(m >> 32);
            if (lane == 2 * c)     keep = lo;
            if (lane == 2 * c + 1) keep = hi;
        }
        if (lane < 6) Pp[s][lane] = keep;
    }

    // ---- Phase B: masks for this wave's j ----
    {
        const int* ndr = &nd[(size_t)j * NN];
        #pragma unroll
        for (int c = 0; c < 3; ++c) {
            const int ndv = ndr[c * 64 + lane];
            unsigned wlo = 0, whi = 0;
            #pragma unroll
            for (int r = 0; r < DD; ++r) {
                const ull m = __ballot(ndv == r);
                if (lane == r) { wlo = (unsigned)m; whi = (unsigned)(m >> 32); }
            }
            if (lane < DD) {
                Msk[wv][lane][2 * c]     = wlo;
                Msk[wv][lane][2 * c + 1] = whi;
            }
        }
    }
    __syncthreads();

    // ---- Phase B2: negated popcounts (192 threads: one per (j_local, r)) ----
    if (tid < 8 * DD) {
        const int jl = tid / DD, r = tid % DD;
        int cnt = 0;
        #pragma unroll
        for (int w = 0; w < 6; ++w) cnt += __popc(Msk[jl][r][w]);
        Msk[jl][r][6] = __float_as_uint(-(float)cnt);
    }
    __syncthreads();

    // ---- Phase C ----
    const unsigned p0 = Pp[lane][0], p1 = Pp[lane][1], p2 = Pp[lane][2];
    const unsigned p3 = Pp[lane][3], p4 = Pp[lane][4], p5 = Pp[lane][5];

    float c[DD];
    #pragma unroll
    for (int r = 0; r < DD; ++r) {
        const unsigned m0 = Msk[wv][r][0], m1 = Msk[wv][r][1], m2 = Msk[wv][r][2];
        const unsigned m3 = Msk[wv][r][3], m4 = Msk[wv][r][4], m5 = Msk[wv][r][5];
        const float ncnt  = __uint_as_float(Msk[wv][r][6]);
        const int pc = __popc(m0 & p0) + __popc(m1 & p1) + __popc(m2 & p2)
                     + __popc(m3 & p3) + __popc(m4 & p4) + __popc(m5 & p5);
        c[r] = fmaf(2.0f, (float)pc, ncnt);
    }

    // quadratic form + W2 dot; W3/W2 uniform-addressed -> scalar-pipe operands
    float q = 0.0f, l2 = 0.0f;
    #pragma unroll
    for (int r = 0; r < DD; ++r) {
        float t = 0.0f;
        #pragma unroll
        for (int s = 0; s < DD; ++s) t = fmaf(W3[r * DD + s], c[s], t);
        q  = fmaf(c[r], t, q);
        l2 = fmaf(W2[r], c[r], l2);
    }

    // sign of x[n, j] = bit j of P; phi-log folded in per (n, j)
    const int w = j >> 5, bpos = j & 31;
    unsigned pw = (w == 0) ? p0 : (w == 1) ? p1 : (w == 2) ? p2
                : (w == 3) ? p3 : (w == 4) ? p4 : p5;
    const int   pos = (int)((pw >> bpos) & 1u);
    const float xj  = pos ? 1.0f : -1.0f;
    const float lp0 = logf(phi[j * 2 + 0]);
    const float lp1 = logf(phi[j * 2 + 1]);

    const float acc = xj * fmaf(0.5f, l2, q) + (pos ? lp1 : lp0);

    part[wv][lane] = acc;
    __syncthreads();
    if (wv == 0) {
        float s = part[0][lane] + part[1][lane] + part[2][lane] + part[3][lane]
                + part[4][lane] + part[5][lane] + part[6][lane] + part[7][lane];
        unsafeAtomicAdd(&out[n0 + lane], s);   // 24 blocks per n
    }
}

extern "C" void kernel_launch(void* const* d_in, const int* in_sizes, int n_in,
                              void* d_out, int out_size, void* d_ws, size_t ws_size,
                              hipStream_t stream) {
    const float* x   = (const float*)d_in[0];
    const float* W2  = (const float*)d_in[1];
    const float* W3  = (const float*)d_in[2];
    const float* phi = (const float*)d_in[3];
    const int*   nd  = (const int*)d_in[4];
    float* out = (float*)d_out;

    const int ns = in_sizes[0] / NN;   // 1024
    hipMemsetAsync(out, 0, (size_t)ns * sizeof(float), stream);
    fused_kernel<<<dim3(ns / 64, NN / 8), 512, 0, stream>>>(x, W2, W3, phi, nd, out);
}

// Round 6
// 31.845 us; speedup vs baseline: 1.1005x; 1.1005x over previous
//
#include <hip/hip_runtime.h>
#include <math.h>

// Dims fixed by reference setup_inputs():
//   x   : (NS=1024, NN=192) f32 in {-1,+1}
//   W2  : (DD=24)           f32
//   W3  : (DD, DD)          f32
//   phi : (NN, 2)           f32
//   nd  : (NN, NN)          i32 in [0, DD), SYMMETRIC
// out  : (NS,) f32 = J2 + J3 + logmf
//
// c[j,r] = sum_i x_i [nd[j,i]==r] = 2*popc(M[j][r] & P[n]) - popc(M[j][r])
// out[n] = sum_j [ x_j*(0.5*<c_j,W2> + c_j^T W3 c_j) + log(phi[j, x_j>0]) ]
//
// Two kernel nodes, no atomics, no memsets (both poison-safe):
//   K1: grid (16,24), 512 thr. Block (bx,by): samples bx*64..+63, wave wv owns
//       j = by*8+wv. Ballot-built masks, popcount c[], scalar-pipe W3 quad
//       form, logmf folded in. Block partial -> PLAIN STORE to ws[by][n].
//   K2: out[n] = sum_{g<24} ws[g][n]  (plain store).

#define NS 1024
#define NN 192
#define DD 24

typedef unsigned long long ull;

__global__ __launch_bounds__(512) void fused_kernel(
    const float* __restrict__ x,
    const float* __restrict__ W2,
    const float* __restrict__ W3,
    const float* __restrict__ phi,
    const int*   __restrict__ nd,
    float* __restrict__ partial)    // ws: [24][NS] f32
{
    const int tid  = threadIdx.x;
    const int lane = tid & 63;
    const int wv   = tid >> 6;          // 0..7
    const int n0   = blockIdx.x * 64;
    const int by   = blockIdx.y;
    const int j    = by * 8 + wv;       // wave-uniform

    __shared__ unsigned Pp[64][6];      // sign bits per sample
    __shared__ unsigned Msk[8][24][8];  // per-j,r: 6 mask words, [6]=-(float)cnt
    __shared__ float    part[8][64];

    // ---- Phase A: wave wv packs samples wv*8 .. wv*8+7 ----
    #pragma unroll
    for (int q = 0; q < 8; ++q) {
        const int s = wv * 8 + q;
        const float* xr = &x[(size_t)(n0 + s) * NN];
        unsigned keep = 0;
        #pragma unroll
        for (int c = 0; c < 3; ++c) {
            const float v = xr[c * 64 + lane];
            const ull m = __ballot(v > 0.0f);
            const unsigned lo = (unsigned)m, hi = (unsigned)(m >> 32);
            if (lane == 2 * c)     keep = lo;
            if (lane == 2 * c + 1) keep = hi;
        }
        if (lane < 6) Pp[s][lane] = keep;
    }

    // ---- Phase B: masks for this wave's j ----
    {
        const int* ndr = &nd[(size_t)j * NN];
        #pragma unroll
        for (int c = 0; c < 3; ++c) {
            const int ndv = ndr[c * 64 + lane];
            unsigned wlo = 0, whi = 0;
            #pragma unroll
            for (int r = 0; r < DD; ++r) {
                const ull m = __ballot(ndv == r);
                if (lane == r) { wlo = (unsigned)m; whi = (unsigned)(m >> 32); }
            }
            if (lane < DD) {
                Msk[wv][lane][2 * c]     = wlo;
                Msk[wv][lane][2 * c + 1] = whi;
            }
        }
    }
    __syncthreads();

    // ---- Phase B2: negated popcounts (one thread per (j_local, r)) ----
    if (tid < 8 * DD) {
        const int jl = tid / DD, r = tid % DD;
        int cnt = 0;
        #pragma unroll
        for (int w = 0; w < 6; ++w) cnt += __popc(Msk[jl][r][w]);
        Msk[jl][r][6] = __float_as_uint(-(float)cnt);
    }
    __syncthreads();

    // ---- Phase C ----
    const unsigned p0 = Pp[lane][0], p1 = Pp[lane][1], p2 = Pp[lane][2];
    const unsigned p3 = Pp[lane][3], p4 = Pp[lane][4], p5 = Pp[lane][5];

    float c[DD];
    #pragma unroll
    for (int r = 0; r < DD; ++r) {
        const unsigned m0 = Msk[wv][r][0], m1 = Msk[wv][r][1], m2 = Msk[wv][r][2];
        const unsigned m3 = Msk[wv][r][3], m4 = Msk[wv][r][4], m5 = Msk[wv][r][5];
        const float ncnt  = __uint_as_float(Msk[wv][r][6]);
        const int pc = __popc(m0 & p0) + __popc(m1 & p1) + __popc(m2 & p2)
                     + __popc(m3 & p3) + __popc(m4 & p4) + __popc(m5 & p5);
        c[r] = fmaf(2.0f, (float)pc, ncnt);
    }

    // quadratic form + W2 dot; W3/W2 uniform-addressed -> scalar-pipe operands
    float q = 0.0f, l2 = 0.0f;
    #pragma unroll
    for (int r = 0; r < DD; ++r) {
        float t = 0.0f;
        #pragma unroll
        for (int s = 0; s < DD; ++s) t = fmaf(W3[r * DD + s], c[s], t);
        q  = fmaf(c[r], t, q);
        l2 = fmaf(W2[r], c[r], l2);
    }

    // sign of x[n, j] = bit j of P; phi-log folded in per (n, j)
    const int w = j >> 5, bpos = j & 31;
    unsigned pw = (w == 0) ? p0 : (w == 1) ? p1 : (w == 2) ? p2
                : (w == 3) ? p3 : (w == 4) ? p4 : p5;
    const int   pos = (int)((pw >> bpos) & 1u);
    const float xj  = pos ? 1.0f : -1.0f;
    const float lp0 = logf(phi[j * 2 + 0]);
    const float lp1 = logf(phi[j * 2 + 1]);

    const float acc = xj * fmaf(0.5f, l2, q) + (pos ? lp1 : lp0);

    part[wv][lane] = acc;
    __syncthreads();
    if (wv == 0) {
        float s = part[0][lane] + part[1][lane] + part[2][lane] + part[3][lane]
                + part[4][lane] + part[5][lane] + part[6][lane] + part[7][lane];
        partial[by * NS + n0 + lane] = s;   // plain store, no atomic
    }
}

__global__ __launch_bounds__(256) void reduce_kernel(
    const float* __restrict__ partial,   // [24][NS]
    float* __restrict__ out)             // [NS]
{
    const int n = blockIdx.x * 256 + threadIdx.x;
    float s = 0.0f;
    #pragma unroll
    for (int g = 0; g < 24; ++g) s += partial[g * NS + n];  // coalesced per g
    out[n] = s;
}

extern "C" void kernel_launch(void* const* d_in, const int* in_sizes, int n_in,
                              void* d_out, int out_size, void* d_ws, size_t ws_size,
                              hipStream_t stream) {
    const float* x   = (const float*)d_in[0];
    const float* W2  = (const float*)d_in[1];
    const float* W3  = (const float*)d_in[2];
    const float* phi = (const float*)d_in[3];
    const int*   nd  = (const int*)d_in[4];
    float* out = (float*)d_out;
    float* partial = (float*)d_ws;   // 24*NS*4 = 96 KB

    const int ns = in_sizes[0] / NN;   // 1024
    fused_kernel<<<dim3(ns / 64, NN / 8), 512, 0, stream>>>(x, W2, W3, phi, nd, partial);
    reduce_kernel<<<ns / 256, 256, 0, stream>>>(partial, out);
}